// Round 2
// baseline (3913.351 us; speedup 1.0000x reference)
//
#include <hip/hip_runtime.h>
#include <math.h>

#define N_   64
#define CIN  64
#define T_   256
#define V_   17
#define OUT_ 128
#define KS   3
#define TV   4352   // T_*V_
#define VV   289    // V_*V_

static __device__ __forceinline__ int rf(int x){ return __builtin_amdgcn_readfirstlane(x); }

static __device__ __forceinline__ unsigned bf16r(float x){
  unsigned u = __float_as_uint(x);
  return (u + 0x7fffu + ((u>>16)&1u)) >> 16;   // RNE to bf16 (no NaN expected)
}

// ---------------- K1: xbar[n,c,v] = mean_t x0[n,c,t,v] ----------------
__global__ void k1_pool(const float* __restrict__ x0, float* __restrict__ xbar){
  int bid = blockIdx.x;            // n*64+c
  int v = threadIdx.x;             // 0..16
  int i = threadIdx.y;             // 0..14
  const float* plane = x0 + (size_t)bid*TV;
  float s = 0.f;
  for(int t=i; t<T_; t+=15) s += plane[t*V_+v];
  __shared__ float red[15*17];
  red[i*17+v] = s;
  __syncthreads();
  if(i==0){
    float tot=0.f;
    #pragma unroll
    for(int ii=0; ii<15; ++ii) tot += red[ii*17+v];
    xbar[bid*V_+v] = tot*(1.f/(float)T_);
  }
}

// ---------------- K2a: weight prep (n-independent) ----------------
// AtileP layout: [kk][g][v][20], class stride 340 (bank-disjoint quads for b128)
__global__ void k2a_prep(const float* __restrict__ conv_w, const float* __restrict__ conv_b,
                         const float* __restrict__ down_w,
                         const float* __restrict__ A_GEME, const float* __restrict__ A_SE,
                         float* __restrict__ convwT, float* __restrict__ Wq, float* __restrict__ Wk,
                         float* __restrict__ bq, float* __restrict__ bk, float* __restrict__ AtileP){
  int tid = threadIdx.x;
  for(int idx=tid; idx<CIN*512; idx+=256){
    int ci = idx>>9, r = idx&511;
    convwT[idx] = (r<384)? conv_w[r*CIN+ci] : down_w[(r-384)*CIN+ci];
  }
  for(int idx=tid; idx<12*CIN; idx+=256){
    int kq = idx>>6, ci = idx&63;
    int k = kq>>2, qq = kq&3;
    int base = k*128 + qq*32;
    float sq=0.f, sk=0.f;
    for(int o=0;o<16;++o){ sq += conv_w[(base+o)*CIN+ci]; sk += conv_w[(base+16+o)*CIN+ci]; }
    Wq[idx] = sq*(1.f/16.f); Wk[idx] = sk*(1.f/16.f);
  }
  if(tid<12){
    int k = tid>>2, qq = tid&3; int base = k*128+qq*32;
    float sq=0.f, sk=0.f;
    for(int o=0;o<16;++o){ sq += conv_b[base+o]; sk += conv_b[base+16+o]; }
    bq[tid]=sq*(1.f/16.f); bk[tid]=sk*(1.f/16.f);
  }
  for(int idx=tid; idx<KS*8*VV; idx+=256){
    int m = idx/VV, rem = idx%VV;
    int v = rem/17, w = rem%17;
    AtileP[m*340 + v*20 + w] = A_SE[idx]+A_GEME[idx];
  }
}

// ---------------- K2b: per-n attention -> attenh[n][kk][q][v][20] (= 0.5*atten) ----------------
__global__ __launch_bounds__(256) void k2b_atten(
    const float* __restrict__ xbar,
    const float* __restrict__ Wq, const float* __restrict__ Wk,
    const float* __restrict__ bq, const float* __restrict__ bk,
    const float* __restrict__ W_spa, const float* __restrict__ b_spa,
    const float* __restrict__ W_mix, const float* __restrict__ b_mix,
    float* __restrict__ attenh){
  __shared__ float xb[CIN*V_];
  __shared__ float lWq[12*CIN], lWk[12*CIN], lbq[12], lbk[12];
  __shared__ float lWs[VV], lbs[V_], lWm[VV], lbm[V_];
  __shared__ float Qb[12*V_], Kb[12*V_], Qs[12*V_], Ks_[12*V_], Km[12*V_], Qm[12*V_];
  __shared__ float Sb[12*VV], Cb[9*VV];
  int tid = threadIdx.x;
  int n = blockIdx.x;
  for(int i=tid;i<CIN*V_;i+=256) xb[i]=xbar[n*CIN*V_+i];
  for(int i=tid;i<12*CIN;i+=256){ lWq[i]=Wq[i]; lWk[i]=Wk[i]; }
  if(tid<12){ lbq[tid]=bq[tid]; lbk[tid]=bk[tid]; }
  for(int i=tid;i<VV;i+=256){ lWs[i]=W_spa[i]; lWm[i]=W_mix[i]; }
  if(tid<V_){ lbs[tid]=b_spa[tid]; lbm[tid]=b_mix[tid]; }
  __syncthreads();
  if(tid<204){
    int kq=tid/17, v=tid%17;
    float qv=lbq[kq], kv=lbk[kq];
    for(int ci=0;ci<CIN;++ci){
      float xv = xb[ci*V_+v];
      qv += lWq[kq*CIN+ci]*xv;
      kv += lWk[kq*CIN+ci]*xv;
    }
    Qb[tid]=qv; Kb[tid]=kv;
  }
  __syncthreads();
  if(tid<204){
    int kq=tid/17, v=tid%17;
    float qs=lbs[v], ks=lbs[v], km=lbm[v], qm=lbm[v];
    #pragma unroll
    for(int u=0;u<V_;++u){
      float ws = lWs[v*V_+u], wm = lWm[v*V_+u];
      float qbu = Qb[kq*V_+u], kbu = Kb[kq*V_+u];
      qs += ws*qbu;
      ks += ws*kbu;
      km += wm*kbu;
      qm += wm*qbu;
    }
    Qs[tid]=fmaxf(qs,0.f); Ks_[tid]=fmaxf(ks,0.f); Km[tid]=fmaxf(km,0.f); Qm[tid]=fmaxf(qm,0.f);
  }
  __syncthreads();
  if(tid<204){
    int kq=tid/17, v=tid%17;
    float a=Qs[tid];
    float e[17]; float mx=-1e30f;
    #pragma unroll
    for(int w=0;w<V_;++w){ e[w]=a*Ks_[kq*V_+w]; mx=fmaxf(mx,e[w]); }
    float s=0.f;
    #pragma unroll
    for(int w=0;w<V_;++w){ e[w]=expf(e[w]-mx); s+=e[w]; }
    float inv=0.25f/s;
    #pragma unroll
    for(int w=0;w<V_;++w) Sb[kq*VV+v*V_+w]=e[w]*inv;
  }
  __syncthreads();
  if(tid<153){
    int kj=tid/17, v=tid%17;
    int k=kj/3, j=kj%3;
    float a=Km[(k*4+j)*V_+v];
    float e[17]; float mx=-1e30f;
    #pragma unroll
    for(int w=0;w<V_;++w){ e[w]=a*Qm[(k*4+j+1)*V_+w]; mx=fmaxf(mx,e[w]); }
    float s=0.f;
    #pragma unroll
    for(int w=0;w<V_;++w){ e[w]=expf(e[w]-mx); s+=e[w]; }
    float inv=0.125f/s;
    #pragma unroll
    for(int w=0;w<V_;++w) Cb[kj*VV+v*V_+w]=e[w]*inv;
  }
  __syncthreads();
  // combine quarters -> padded layout [kk*4+q][v][20]
  for(int idx=tid; idx<KS*4*VV; idx+=256){
    int kq=idx/VV, rem=idx%VV;
    int k=kq>>2, qq=kq&3;
    int v=rem/17, w=rem%17;
    float val=Sb[idx];
    if(qq>0) val += Cb[(k*3+qq-1)*VV+rem];
    if(qq<3) val += Cb[(k*3+qq)*VV+rem];
    attenh[(size_t)n*4080 + kq*340 + v*20 + w]=val;
  }
}

// ---------------- K3: fused conv + graph conv + stats + bf16 pack ----------------
// block = (t-chunk of 4, n); 256 threads = 128 c x 2 t-halves
__global__ __launch_bounds__(256,3) void k3_main(
    const float* __restrict__ x0, const float* __restrict__ convwT,
    const float* __restrict__ conv_b, const float* __restrict__ down_b,
    const float* __restrict__ attenh, const float* __restrict__ AtileP,
    unsigned* __restrict__ mpack,
    float* __restrict__ s1ws, float* __restrict__ s2ws,
    float* __restrict__ dSws, float* __restrict__ dSSws){
  __shared__ float smem[12240];   // atten 4080 | Atile 8160 ; later aliased as staging 128*69
  __shared__ float s1c[128], s2c[128], dSc[128], dSSc[128];
  const int tid = threadIdx.x;
  const int chunk = blockIdx.x, n = blockIdx.y;
  const int t0 = chunk*4;
  const int c = tid & 127;
  const int th = rf(tid>>7);
  const int q = c>>5, g = c&7;

  {
    const float* ag = attenh + (size_t)n*4080;
    for(int i=tid;i<4080;i+=256) smem[i] = ag[i];
    for(int i=tid;i<8160;i+=256) smem[4080+i] = AtileP[i];
  }
  if(tid<128){ s1c[tid]=0.f; s2c[tid]=0.f; dSc[tid]=0.f; dSSc[tid]=0.f; }
  __syncthreads();

  const float* atq = smem + q*340;          // + kk*1360 + v*20 + w
  const float* tig = smem + 4080 + g*340;   // + kk*2720 + v*20 + w
  const float* xbase = x0 + (size_t)n*CIN*TV + (size_t)(t0 + th*2)*V_;

  float p[2][17];
  #pragma unroll
  for(int tl=0;tl<2;++tl)
    #pragma unroll
    for(int w=0;w<V_;++w) p[tl][w]=0.f;

  float accA[2][17], accB[2][17];

  // ================= pass A : kk=0 (accA), kk=1 (accB) =================
  {
    float bA = conv_b[c], bB = conv_b[128+c];
    #pragma unroll
    for(int tl=0;tl<2;++tl)
      #pragma unroll
      for(int v=0;v<V_;++v){ accA[tl][v]=bA; accB[tl][v]=bB; }
    for(int ci=0; ci<CIN; ++ci){
      float wA = convwT[ci*512 + c];
      float wB = convwT[ci*512 + 128 + c];
      const float* xc = xbase + (size_t)ci*TV;
      #pragma unroll
      for(int tl=0;tl<2;++tl)
        #pragma unroll
        for(int v=0;v<V_;++v){
          float xv = xc[tl*V_+v];
          accA[tl][v] = fmaf(wA, xv, accA[tl][v]);
          accB[tl][v] = fmaf(wB, xv, accB[tl][v]);
        }
    }
    // graph kk=0 with accA
    #pragma unroll
    for(int v=0;v<V_;++v){
      float af[17];
      #pragma unroll
      for(int w=0;w<V_;++w) af[w] = atq[v*20+w] + tig[v*20+w];
      #pragma unroll
      for(int w=0;w<V_;++w){
        p[0][w] = fmaf(accA[0][v], af[w], p[0][w]);
        p[1][w] = fmaf(accA[1][v], af[w], p[1][w]);
      }
    }
    // graph kk=1 with accB
    #pragma unroll
    for(int v=0;v<V_;++v){
      float af[17];
      #pragma unroll
      for(int w=0;w<V_;++w) af[w] = atq[1360 + v*20+w] + tig[2720 + v*20+w];
      #pragma unroll
      for(int w=0;w<V_;++w){
        p[0][w] = fmaf(accB[0][v], af[w], p[0][w]);
        p[1][w] = fmaf(accB[1][v], af[w], p[1][w]);
      }
    }
  }

  // ================= pass B : kk=2 (accA), down (accB) =================
  {
    float bA = conv_b[256+c], bB = down_b[c];
    #pragma unroll
    for(int tl=0;tl<2;++tl)
      #pragma unroll
      for(int v=0;v<V_;++v){ accA[tl][v]=bA; accB[tl][v]=bB; }
    for(int ci=0; ci<CIN; ++ci){
      float wA = convwT[ci*512 + 256 + c];
      float wB = convwT[ci*512 + 384 + c];
      const float* xc = xbase + (size_t)ci*TV;
      #pragma unroll
      for(int tl=0;tl<2;++tl)
        #pragma unroll
        for(int v=0;v<V_;++v){
          float xv = xc[tl*V_+v];
          accA[tl][v] = fmaf(wA, xv, accA[tl][v]);
          accB[tl][v] = fmaf(wB, xv, accB[tl][v]);
        }
    }
    // graph kk=2 with accA
    #pragma unroll
    for(int v=0;v<V_;++v){
      float af[17];
      #pragma unroll
      for(int w=0;w<V_;++w) af[w] = atq[2720 + v*20+w] + tig[5440 + v*20+w];
      #pragma unroll
      for(int w=0;w<V_;++w){
        p[0][w] = fmaf(accA[0][v], af[w], p[0][w]);
        p[1][w] = fmaf(accA[1][v], af[w], p[1][w]);
      }
    }
  }

  // ---- stats on bf16-rounded values + pack ----
  unsigned pk[2][17];
  {
    float s=0.f, ss=0.f, sd=0.f, ssd=0.f;
    #pragma unroll
    for(int tl=0;tl<2;++tl)
      #pragma unroll
      for(int v=0;v<V_;++v){
        unsigned um = bf16r(p[tl][v]);
        unsigned ud = bf16r(accB[tl][v]);
        float rm = __uint_as_float(um<<16);
        float rd = __uint_as_float(ud<<16);
        pk[tl][v] = um | (ud<<16);
        s += rm; ss = fmaf(rm,rm,ss); sd += rd; ssd = fmaf(rd,rd,ssd);
      }
    atomicAdd(&s1c[c], s); atomicAdd(&s2c[c], ss);
    atomicAdd(&dSc[c], sd); atomicAdd(&dSSc[c], ssd);
  }
  __syncthreads();   // tables fully consumed, LDS stats complete
  {
    unsigned* stg = (unsigned*)smem;   // [c][69] padded: bank stride 5 -> conflict-free
    #pragma unroll
    for(int tl=0;tl<2;++tl)
      #pragma unroll
      for(int v=0;v<V_;++v)
        stg[c*69 + (th*2+tl)*V_ + v] = pk[tl][v];
  }
  if(tid<128){
    atomicAdd(&s1ws[n*128+tid], s1c[tid]);
    atomicAdd(&s2ws[n*128+tid], s2c[tid]);
    atomicAdd(&dSws[tid], dSc[tid]);
    atomicAdd(&dSSws[tid], dSSc[tid]);
  }
  __syncthreads();
  {
    const unsigned* stg = (const unsigned*)smem;
    for(int idx=tid; idx<128*68; idx+=256){
      int cc = idx/68, r = idx - cc*68;
      mpack[(size_t)(n*128+cc)*TV + (size_t)t0*V_ + r] = stg[cc*69+r];
    }
  }
}

// ---------------- K4: gate + BN coefficient finalize ----------------
__global__ void k4_stats(const float* __restrict__ s1ws, const float* __restrict__ s2ws,
                         const float* __restrict__ dSws, const float* __restrict__ dSSws,
                         const float* __restrict__ charef_w,
                         const float* __restrict__ bn_gamma, const float* __restrict__ bn_beta,
                         const float* __restrict__ down_bn_gamma, const float* __restrict__ down_bn_beta,
                         float* __restrict__ g1ws, float* __restrict__ coef){
  int c = threadIdx.x;  // 128 threads
  float w0=charef_w[0], w1=charef_w[1], w2=charef_w[2];
  const float invTV = 1.f/(float)TV;
  float Sm=0.f, Sq=0.f;
  for(int n=0;n<N_;++n){
    float s1 = s1ws[n*128+c];
    float cr  = s1*invTV;
    float crm = (c>0)?   s1ws[n*128+c-1]*invTV : 0.f;
    float crp = (c<127)? s1ws[n*128+c+1]*invTV : 0.f;
    float cc = w0*crm + w1*cr + w2*crp;
    float g1 = 1.f + 1.f/(1.f+expf(-cc));   // 1 + sigmoid
    g1ws[n*128+c] = g1;
    Sm += s1*g1;
    Sq += s2ws[n*128+c]*g1*g1;
  }
  const float invNTV = 1.f/((float)N_*(float)TV);
  float mean = Sm*invNTV;
  float var  = Sq*invNTV - mean*mean;
  float sc = bn_gamma[c]*rsqrtf(var+1e-5f);
  coef[c]     = sc;
  coef[128+c] = bn_beta[c] - mean*sc;
  float mD = dSws[c]*invNTV;
  float vD = dSSws[c]*invNTV - mD*mD;
  float scD = down_bn_gamma[c]*rsqrtf(vD+1e-5f);
  coef[256+c] = scD;
  coef[384+c] = down_bn_beta[c] - mD*scD;
}

// ---------------- K5: elementwise unpack + affine + relu (in-place on d_out) ----------------
__global__ __launch_bounds__(256) void k5_out(
    const unsigned* mpack, const float* __restrict__ g1ws,
    const float* __restrict__ coef, float* out){
  int plane = blockIdx.x;          // n*128 + c
  int c = plane & 127;
  float a1  = coef[c] * g1ws[plane];
  float scD = coef[256+c];
  float b   = coef[128+c] + coef[384+c];
  const uint4* src = (const uint4*)(mpack + (size_t)plane*TV);
  float4* dst = (float4*)(out + (size_t)plane*TV);
  for(int i=threadIdx.x; i<TV/4; i+=256){
    uint4 w = src[i];
    float4 r;
    r.x = fmaxf(fmaf(a1, __uint_as_float(w.x<<16), fmaf(scD, __uint_as_float(w.x&0xffff0000u), b)), 0.f);
    r.y = fmaxf(fmaf(a1, __uint_as_float(w.y<<16), fmaf(scD, __uint_as_float(w.y&0xffff0000u), b)), 0.f);
    r.z = fmaxf(fmaf(a1, __uint_as_float(w.z<<16), fmaf(scD, __uint_as_float(w.z&0xffff0000u), b)), 0.f);
    r.w = fmaxf(fmaf(a1, __uint_as_float(w.w<<16), fmaf(scD, __uint_as_float(w.w&0xffff0000u), b)), 0.f);
    dst[i] = r;
  }
}

extern "C" void kernel_launch(void* const* d_in, const int* in_sizes, int n_in,
                              void* d_out, int out_size, void* d_ws, size_t ws_size,
                              hipStream_t stream){
  const float* x0      = (const float*)d_in[0];
  const float* conv_w  = (const float*)d_in[1];
  const float* conv_b  = (const float*)d_in[2];
  const float* W_spa   = (const float*)d_in[3];
  const float* b_spa   = (const float*)d_in[4];
  const float* W_mix   = (const float*)d_in[5];
  const float* b_mix   = (const float*)d_in[6];
  const float* A_GEME  = (const float*)d_in[7];
  const float* A_SE    = (const float*)d_in[8];
  const float* charef_w= (const float*)d_in[9];
  const float* bn_gamma= (const float*)d_in[10];
  const float* bn_beta = (const float*)d_in[11];
  const float* down_w  = (const float*)d_in[12];
  const float* down_b  = (const float*)d_in[13];
  const float* down_bn_gamma = (const float*)d_in[14];
  const float* down_bn_beta  = (const float*)d_in[15];
  float* out = (float*)d_out;
  float* ws  = (float*)d_ws;

  float* xbar   = ws;                 // 69632
  float* convwT = xbar + 69632;       // 32768
  float* Wq     = convwT + 32768;     // 768
  float* Wk     = Wq + 768;           // 768
  float* bq     = Wk + 768;           // 12
  float* bk     = bq + 12;            // 12
  float* AtileP = bk + 12;            // 8160
  float* attenh = AtileP + 8160;      // 64*4080 = 261120
  float* s1ws   = attenh + 261120;    // 8192  -- accumulators (memset region start)
  float* s2ws   = s1ws + 8192;        // 8192
  float* dSws   = s2ws + 8192;        // 128
  float* dSSws  = dSws + 128;         // 128   -- memset region end (16640 floats)
  float* g1ws   = dSSws + 128;        // 8192
  float* coef   = g1ws + 8192;        // 512

  hipMemsetAsync(s1ws, 0, (size_t)16640*sizeof(float), stream);
  k1_pool<<<dim3(N_*CIN), dim3(17,15), 0, stream>>>(x0, xbar);
  k2a_prep<<<1, 256, 0, stream>>>(conv_w, conv_b, down_w, A_GEME, A_SE,
                                  convwT, Wq, Wk, bq, bk, AtileP);
  k2b_atten<<<N_, 256, 0, stream>>>(xbar, Wq, Wk, bq, bk, W_spa, b_spa, W_mix, b_mix, attenh);
  k3_main<<<dim3(64, N_), 256, 0, stream>>>(x0, convwT, conv_b, down_b, attenh, AtileP,
                                            (unsigned*)out, s1ws, s2ws, dSws, dSSws);
  k4_stats<<<1, 128, 0, stream>>>(s1ws, s2ws, dSws, dSSws, charef_w,
                                  bn_gamma, bn_beta, down_bn_gamma, down_bn_beta, g1ws, coef);
  k5_out<<<dim3(N_*OUT_), 256, 0, stream>>>((const unsigned*)out, g1ws, coef, out);
}

// Round 3
// 910.523 us; speedup vs baseline: 4.2979x; 4.2979x over previous
//
#include <hip/hip_runtime.h>
#include <math.h>

#define N_   64
#define CIN  64
#define T_   256
#define V_   17
#define OUT_ 128
#define KS   3
#define TV   4352   // T_*V_
#define VV   289    // V_*V_

static __device__ __forceinline__ int rf(int x){ return __builtin_amdgcn_readfirstlane(x); }

static __device__ __forceinline__ unsigned bf16r(float x){
  unsigned u = __float_as_uint(x);
  return (u + 0x7fffu + ((u>>16)&1u)) >> 16;   // RNE to bf16 (no NaN expected)
}

// ---------------- K1: xbar[n,c,v] = mean_t x0[n,c,t,v] ----------------
__global__ void k1_pool(const float* __restrict__ x0, float* __restrict__ xbar){
  int bid = blockIdx.x;            // n*64+c
  int v = threadIdx.x;             // 0..16
  int i = threadIdx.y;             // 0..14
  const float* plane = x0 + (size_t)bid*TV;
  float s = 0.f;
  for(int t=i; t<T_; t+=15) s += plane[t*V_+v];
  __shared__ float red[15*17];
  red[i*17+v] = s;
  __syncthreads();
  if(i==0){
    float tot=0.f;
    #pragma unroll
    for(int ii=0; ii<15; ++ii) tot += red[ii*17+v];
    xbar[bid*V_+v] = tot*(1.f/(float)T_);
  }
}

// ---------------- K2a: weight prep (n-independent) ----------------
// AtileP layout: [kk][g][v][20], class stride 340
__global__ void k2a_prep(const float* __restrict__ conv_w, const float* __restrict__ conv_b,
                         const float* __restrict__ down_w,
                         const float* __restrict__ A_GEME, const float* __restrict__ A_SE,
                         float* __restrict__ convwT, float* __restrict__ Wq, float* __restrict__ Wk,
                         float* __restrict__ bq, float* __restrict__ bk, float* __restrict__ AtileP){
  int tid = threadIdx.x;
  for(int idx=tid; idx<CIN*512; idx+=256){
    int ci = idx>>9, r = idx&511;
    convwT[idx] = (r<384)? conv_w[r*CIN+ci] : down_w[(r-384)*CIN+ci];
  }
  for(int idx=tid; idx<12*CIN; idx+=256){
    int kq = idx>>6, ci = idx&63;
    int k = kq>>2, qq = kq&3;
    int base = k*128 + qq*32;
    float sq=0.f, sk=0.f;
    for(int o=0;o<16;++o){ sq += conv_w[(base+o)*CIN+ci]; sk += conv_w[(base+16+o)*CIN+ci]; }
    Wq[idx] = sq*(1.f/16.f); Wk[idx] = sk*(1.f/16.f);
  }
  if(tid<12){
    int k = tid>>2, qq = tid&3; int base = k*128+qq*32;
    float sq=0.f, sk=0.f;
    for(int o=0;o<16;++o){ sq += conv_b[base+o]; sk += conv_b[base+16+o]; }
    bq[tid]=sq*(1.f/16.f); bk[tid]=sk*(1.f/16.f);
  }
  for(int idx=tid; idx<KS*8*VV; idx+=256){
    int m = idx/VV, rem = idx%VV;
    int v = rem/17, w = rem%17;
    AtileP[m*340 + v*20 + w] = A_SE[idx]+A_GEME[idx];
  }
}

// ---------------- K2b: per-n attention -> attenh[n][kk][q][v][20] (= 0.5*atten) ----------------
__global__ __launch_bounds__(256) void k2b_atten(
    const float* __restrict__ xbar,
    const float* __restrict__ Wq, const float* __restrict__ Wk,
    const float* __restrict__ bq, const float* __restrict__ bk,
    const float* __restrict__ W_spa, const float* __restrict__ b_spa,
    const float* __restrict__ W_mix, const float* __restrict__ b_mix,
    float* __restrict__ attenh){
  __shared__ float xb[CIN*V_];
  __shared__ float lWq[12*CIN], lWk[12*CIN], lbq[12], lbk[12];
  __shared__ float lWs[VV], lbs[V_], lWm[VV], lbm[V_];
  __shared__ float Qb[12*V_], Kb[12*V_], Qs[12*V_], Ks_[12*V_], Km[12*V_], Qm[12*V_];
  __shared__ float Sb[12*VV], Cb[9*VV];
  int tid = threadIdx.x;
  int n = blockIdx.x;
  for(int i=tid;i<CIN*V_;i+=256) xb[i]=xbar[n*CIN*V_+i];
  for(int i=tid;i<12*CIN;i+=256){ lWq[i]=Wq[i]; lWk[i]=Wk[i]; }
  if(tid<12){ lbq[tid]=bq[tid]; lbk[tid]=bk[tid]; }
  for(int i=tid;i<VV;i+=256){ lWs[i]=W_spa[i]; lWm[i]=W_mix[i]; }
  if(tid<V_){ lbs[tid]=b_spa[tid]; lbm[tid]=b_mix[tid]; }
  __syncthreads();
  if(tid<204){
    int kq=tid/17, v=tid%17;
    float qv=lbq[kq], kv=lbk[kq];
    for(int ci=0;ci<CIN;++ci){
      float xv = xb[ci*V_+v];
      qv += lWq[kq*CIN+ci]*xv;
      kv += lWk[kq*CIN+ci]*xv;
    }
    Qb[tid]=qv; Kb[tid]=kv;
  }
  __syncthreads();
  if(tid<204){
    int kq=tid/17, v=tid%17;
    float qs=lbs[v], ks=lbs[v], km=lbm[v], qm=lbm[v];
    #pragma unroll
    for(int u=0;u<V_;++u){
      float ws = lWs[v*V_+u], wm = lWm[v*V_+u];
      float qbu = Qb[kq*V_+u], kbu = Kb[kq*V_+u];
      qs += ws*qbu;
      ks += ws*kbu;
      km += wm*kbu;
      qm += wm*qbu;
    }
    Qs[tid]=fmaxf(qs,0.f); Ks_[tid]=fmaxf(ks,0.f); Km[tid]=fmaxf(km,0.f); Qm[tid]=fmaxf(qm,0.f);
  }
  __syncthreads();
  if(tid<204){
    int kq=tid/17, v=tid%17;
    float a=Qs[tid];
    float e[17]; float mx=-1e30f;
    #pragma unroll
    for(int w=0;w<V_;++w){ e[w]=a*Ks_[kq*V_+w]; mx=fmaxf(mx,e[w]); }
    float s=0.f;
    #pragma unroll
    for(int w=0;w<V_;++w){ e[w]=expf(e[w]-mx); s+=e[w]; }
    float inv=0.25f/s;
    #pragma unroll
    for(int w=0;w<V_;++w) Sb[kq*VV+v*V_+w]=e[w]*inv;
  }
  __syncthreads();
  if(tid<153){
    int kj=tid/17, v=tid%17;
    int k=kj/3, j=kj%3;
    float a=Km[(k*4+j)*V_+v];
    float e[17]; float mx=-1e30f;
    #pragma unroll
    for(int w=0;w<V_;++w){ e[w]=a*Qm[(k*4+j+1)*V_+w]; mx=fmaxf(mx,e[w]); }
    float s=0.f;
    #pragma unroll
    for(int w=0;w<V_;++w){ e[w]=expf(e[w]-mx); s+=e[w]; }
    float inv=0.125f/s;
    #pragma unroll
    for(int w=0;w<V_;++w) Cb[kj*VV+v*V_+w]=e[w]*inv;
  }
  __syncthreads();
  for(int idx=tid; idx<KS*4*VV; idx+=256){
    int kq=idx/VV, rem=idx%VV;
    int k=kq>>2, qq=kq&3;
    int v=rem/17, w=rem%17;
    float val=Sb[idx];
    if(qq>0) val += Cb[(k*3+qq-1)*VV+rem];
    if(qq<3) val += Cb[(k*3+qq)*VV+rem];
    attenh[(size_t)n*4080 + kq*340 + v*20 + w]=val;
  }
}

// ---------------- K3: fused conv + graph conv + stats + bf16 pack ----------------
// block = 256 threads = 128 c x 2 t; grid = (T/2, N).
// One acc[17] live at a time -> no VGPR spill (R2 lesson: 3x34 live floats spilled
// to scratch at 84 VGPRs -> 11 GB of scratch traffic).
__global__ __launch_bounds__(256) void k3_main(
    const float* __restrict__ x0, const float* __restrict__ convwT,
    const float* __restrict__ conv_b, const float* __restrict__ down_b,
    const float* __restrict__ attenh, const float* __restrict__ AtileP,
    unsigned* __restrict__ mpack,
    float* __restrict__ s1ws, float* __restrict__ s2ws,
    float* __restrict__ dSws, float* __restrict__ dSSws){
  __shared__ float smem[12240];   // atten 4080 | Atile 8160 ; later aliased as staging [128][35]
  __shared__ float s1c[128], s2c[128], dSc[128], dSSc[128];
  const int tid = threadIdx.x;
  const int chunk = blockIdx.x, n = blockIdx.y;
  const int t0 = chunk*2;
  const int c = tid & 127;
  const int th = rf(tid>>7);           // wave-uniform timestep select
  const int q = c>>5, g = c&7;

  {
    const float* ag = attenh + (size_t)n*4080;
    for(int i=tid;i<4080;i+=256) smem[i] = ag[i];
    for(int i=tid;i<8160;i+=256) smem[4080+i] = AtileP[i];
  }
  if(tid<128){ s1c[tid]=0.f; s2c[tid]=0.f; dSc[tid]=0.f; dSSc[tid]=0.f; }
  __syncthreads();

  const float* atq = smem + q*340;          // + kk*1360 + v*20 + w
  const float* tig = smem + 4080 + g*340;   // + kk*2720 + v*20 + w
  const float* xbase = x0 + (size_t)n*CIN*TV + (size_t)(t0 + th)*V_;  // wave-uniform rows

  float p[17];
  #pragma unroll
  for(int w=0;w<V_;++w) p[w]=0.f;

  // ---- kk = 0..2 : conv acc -> immediately folded into p ----
  for(int kk=0; kk<KS; ++kk){
    float acc[17];
    float b = conv_b[kk*128 + c];
    #pragma unroll
    for(int v=0;v<V_;++v) acc[v]=b;
    for(int ci=0; ci<CIN; ++ci){
      float wv = convwT[ci*512 + kk*128 + c];
      const float* xc = xbase + (size_t)ci*TV;
      #pragma unroll
      for(int v=0;v<V_;++v) acc[v] = fmaf(wv, xc[v], acc[v]);
    }
    const float* a1 = atq + kk*1360;
    const float* a2 = tig + kk*2720;
    #pragma unroll
    for(int v=0;v<V_;++v){
      float mv = acc[v];
      #pragma unroll
      for(int w=0;w<V_;++w)
        p[w] = fmaf(mv, a1[v*20+w] + a2[v*20+w], p[w]);
    }
  }

  // ---- down path ----
  float dn[17];
  {
    float b = down_b[c];
    #pragma unroll
    for(int v=0;v<V_;++v) dn[v]=b;
    for(int ci=0; ci<CIN; ++ci){
      float wv = convwT[ci*512 + 384 + c];
      const float* xc = xbase + (size_t)ci*TV;
      #pragma unroll
      for(int v=0;v<V_;++v) dn[v] = fmaf(wv, xc[v], dn[v]);
    }
  }

  // ---- stats on bf16-rounded values + pack (reuse p storage as pk) ----
  unsigned pk[17];
  {
    float s=0.f, ss=0.f, sd=0.f, ssd=0.f;
    #pragma unroll
    for(int v=0;v<V_;++v){
      unsigned um = bf16r(p[v]);
      unsigned ud = bf16r(dn[v]);
      float rm = __uint_as_float(um<<16);
      float rd = __uint_as_float(ud<<16);
      pk[v] = um | (ud<<16);
      s += rm; ss = fmaf(rm,rm,ss); sd += rd; ssd = fmaf(rd,rd,ssd);
    }
    atomicAdd(&s1c[c], s); atomicAdd(&s2c[c], ss);
    atomicAdd(&dSc[c], sd); atomicAdd(&dSSc[c], ssd);
  }
  __syncthreads();   // tables fully consumed; LDS stats complete
  {
    unsigned* stg = (unsigned*)smem;   // [c][35 pad]
    #pragma unroll
    for(int v=0;v<V_;++v) stg[c*35 + th*V_ + v] = pk[v];
  }
  if(tid<128){
    atomicAdd(&s1ws[n*128+tid], s1c[tid]);
    atomicAdd(&s2ws[n*128+tid], s2c[tid]);
    atomicAdd(&dSws[tid], dSc[tid]);
    atomicAdd(&dSSws[tid], dSSc[tid]);
  }
  __syncthreads();
  {
    const unsigned* stg = (const unsigned*)smem;
    for(int idx=tid; idx<128*34; idx+=256){
      int cc = idx/34, r = idx - cc*34;
      mpack[(size_t)(n*128+cc)*TV + (size_t)t0*V_ + r] = stg[cc*35+r];
    }
  }
}

// ---------------- K4: gate + BN coefficient finalize ----------------
__global__ void k4_stats(const float* __restrict__ s1ws, const float* __restrict__ s2ws,
                         const float* __restrict__ dSws, const float* __restrict__ dSSws,
                         const float* __restrict__ charef_w,
                         const float* __restrict__ bn_gamma, const float* __restrict__ bn_beta,
                         const float* __restrict__ down_bn_gamma, const float* __restrict__ down_bn_beta,
                         float* __restrict__ g1ws, float* __restrict__ coef){
  int c = threadIdx.x;  // 128 threads
  float w0=charef_w[0], w1=charef_w[1], w2=charef_w[2];
  const float invTV = 1.f/(float)TV;
  float Sm=0.f, Sq=0.f;
  for(int n=0;n<N_;++n){
    float s1 = s1ws[n*128+c];
    float cr  = s1*invTV;
    float crm = (c>0)?   s1ws[n*128+c-1]*invTV : 0.f;
    float crp = (c<127)? s1ws[n*128+c+1]*invTV : 0.f;
    float cc = w0*crm + w1*cr + w2*crp;
    float g1 = 1.f + 1.f/(1.f+expf(-cc));   // 1 + sigmoid
    g1ws[n*128+c] = g1;
    Sm += s1*g1;
    Sq += s2ws[n*128+c]*g1*g1;
  }
  const float invNTV = 1.f/((float)N_*(float)TV);
  float mean = Sm*invNTV;
  float var  = Sq*invNTV - mean*mean;
  float sc = bn_gamma[c]*rsqrtf(var+1e-5f);
  coef[c]     = sc;
  coef[128+c] = bn_beta[c] - mean*sc;
  float mD = dSws[c]*invNTV;
  float vD = dSSws[c]*invNTV - mD*mD;
  float scD = down_bn_gamma[c]*rsqrtf(vD+1e-5f);
  coef[256+c] = scD;
  coef[384+c] = down_bn_beta[c] - mD*scD;
}

// ---------------- K5: elementwise unpack + affine + relu (in-place on d_out) ----------------
__global__ __launch_bounds__(256) void k5_out(
    const unsigned* mpack, const float* __restrict__ g1ws,
    const float* __restrict__ coef, float* out){
  int plane = blockIdx.x;          // n*128 + c
  int c = plane & 127;
  float a1  = coef[c] * g1ws[plane];
  float scD = coef[256+c];
  float b   = coef[128+c] + coef[384+c];
  const uint4* src = (const uint4*)(mpack + (size_t)plane*TV);
  float4* dst = (float4*)(out + (size_t)plane*TV);
  for(int i=threadIdx.x; i<TV/4; i+=256){
    uint4 w = src[i];
    float4 r;
    r.x = fmaxf(fmaf(a1, __uint_as_float(w.x<<16), fmaf(scD, __uint_as_float(w.x&0xffff0000u), b)), 0.f);
    r.y = fmaxf(fmaf(a1, __uint_as_float(w.y<<16), fmaf(scD, __uint_as_float(w.y&0xffff0000u), b)), 0.f);
    r.z = fmaxf(fmaf(a1, __uint_as_float(w.z<<16), fmaf(scD, __uint_as_float(w.z&0xffff0000u), b)), 0.f);
    r.w = fmaxf(fmaf(a1, __uint_as_float(w.w<<16), fmaf(scD, __uint_as_float(w.w&0xffff0000u), b)), 0.f);
    dst[i] = r;
  }
}

extern "C" void kernel_launch(void* const* d_in, const int* in_sizes, int n_in,
                              void* d_out, int out_size, void* d_ws, size_t ws_size,
                              hipStream_t stream){
  const float* x0      = (const float*)d_in[0];
  const float* conv_w  = (const float*)d_in[1];
  const float* conv_b  = (const float*)d_in[2];
  const float* W_spa   = (const float*)d_in[3];
  const float* b_spa   = (const float*)d_in[4];
  const float* W_mix   = (const float*)d_in[5];
  const float* b_mix   = (const float*)d_in[6];
  const float* A_GEME  = (const float*)d_in[7];
  const float* A_SE    = (const float*)d_in[8];
  const float* charef_w= (const float*)d_in[9];
  const float* bn_gamma= (const float*)d_in[10];
  const float* bn_beta = (const float*)d_in[11];
  const float* down_w  = (const float*)d_in[12];
  const float* down_b  = (const float*)d_in[13];
  const float* down_bn_gamma = (const float*)d_in[14];
  const float* down_bn_beta  = (const float*)d_in[15];
  float* out = (float*)d_out;
  float* ws  = (float*)d_ws;

  float* xbar   = ws;                 // 69632
  float* convwT = xbar + 69632;       // 32768
  float* Wq     = convwT + 32768;     // 768
  float* Wk     = Wq + 768;           // 768
  float* bq     = Wk + 768;           // 12
  float* bk     = bq + 12;            // 12
  float* AtileP = bk + 12;            // 8160
  float* attenh = AtileP + 8160;      // 64*4080 = 261120
  float* s1ws   = attenh + 261120;    // 8192  -- accumulators (memset region start)
  float* s2ws   = s1ws + 8192;        // 8192
  float* dSws   = s2ws + 8192;        // 128
  float* dSSws  = dSws + 128;         // 128   -- memset region end (16640 floats)
  float* g1ws   = dSSws + 128;        // 8192
  float* coef   = g1ws + 8192;        // 512

  hipMemsetAsync(s1ws, 0, (size_t)16640*sizeof(float), stream);
  k1_pool<<<dim3(N_*CIN), dim3(17,15), 0, stream>>>(x0, xbar);
  k2a_prep<<<1, 256, 0, stream>>>(conv_w, conv_b, down_w, A_GEME, A_SE,
                                  convwT, Wq, Wk, bq, bk, AtileP);
  k2b_atten<<<N_, 256, 0, stream>>>(xbar, Wq, Wk, bq, bk, W_spa, b_spa, W_mix, b_mix, attenh);
  k3_main<<<dim3(T_/2, N_), 256, 0, stream>>>(x0, convwT, conv_b, down_b, attenh, AtileP,
                                              (unsigned*)out, s1ws, s2ws, dSws, dSSws);
  k4_stats<<<1, 128, 0, stream>>>(s1ws, s2ws, dSws, dSSws, charef_w,
                                  bn_gamma, bn_beta, down_bn_gamma, down_bn_beta, g1ws, coef);
  k5_out<<<dim3(N_*OUT_), 256, 0, stream>>>((const unsigned*)out, g1ws, coef, out);
}

// Round 4
// 769.298 us; speedup vs baseline: 5.0869x; 1.1836x over previous
//
#include <hip/hip_runtime.h>
#include <math.h>

#define N_   64
#define CIN  64
#define T_   256
#define V_   17
#define OUT_ 128
#define KS   3
#define TV   4352   // T_*V_
#define VV   289    // V_*V_

static __device__ __forceinline__ int rf(int x){ return __builtin_amdgcn_readfirstlane(x); }

static __device__ __forceinline__ unsigned bf16r(float x){
  unsigned u = __float_as_uint(x);
  return (u + 0x7fffu + ((u>>16)&1u)) >> 16;   // RNE to bf16 (no NaN expected)
}

// ---------------- K1: xbar[n,c,v] = mean_t x0[n,c,t,v] ----------------
__global__ void k1_pool(const float* __restrict__ x0, float* __restrict__ xbar){
  int bid = blockIdx.x;            // n*64+c
  int v = threadIdx.x;             // 0..16
  int i = threadIdx.y;             // 0..14
  const float* plane = x0 + (size_t)bid*TV;
  float s = 0.f;
  for(int t=i; t<T_; t+=15) s += plane[t*V_+v];
  __shared__ float red[15*17];
  red[i*17+v] = s;
  __syncthreads();
  if(i==0){
    float tot=0.f;
    #pragma unroll
    for(int ii=0; ii<15; ++ii) tot += red[ii*17+v];
    xbar[bid*V_+v] = tot*(1.f/(float)T_);
  }
}

// ---------------- K2a: weight prep (n-independent) ----------------
// AtileP layout: [kk][g][v][20], class stride 340
__global__ void k2a_prep(const float* __restrict__ conv_w, const float* __restrict__ conv_b,
                         const float* __restrict__ down_w,
                         const float* __restrict__ A_GEME, const float* __restrict__ A_SE,
                         float* __restrict__ convwT, float* __restrict__ Wq, float* __restrict__ Wk,
                         float* __restrict__ bq, float* __restrict__ bk, float* __restrict__ AtileP){
  int tid = threadIdx.x;
  for(int idx=tid; idx<CIN*512; idx+=256){
    int ci = idx>>9, r = idx&511;
    convwT[idx] = (r<384)? conv_w[r*CIN+ci] : down_w[(r-384)*CIN+ci];
  }
  for(int idx=tid; idx<12*CIN; idx+=256){
    int kq = idx>>6, ci = idx&63;
    int k = kq>>2, qq = kq&3;
    int base = k*128 + qq*32;
    float sq=0.f, sk=0.f;
    for(int o=0;o<16;++o){ sq += conv_w[(base+o)*CIN+ci]; sk += conv_w[(base+16+o)*CIN+ci]; }
    Wq[idx] = sq*(1.f/16.f); Wk[idx] = sk*(1.f/16.f);
  }
  if(tid<12){
    int k = tid>>2, qq = tid&3; int base = k*128+qq*32;
    float sq=0.f, sk=0.f;
    for(int o=0;o<16;++o){ sq += conv_b[base+o]; sk += conv_b[base+16+o]; }
    bq[tid]=sq*(1.f/16.f); bk[tid]=sk*(1.f/16.f);
  }
  for(int idx=tid; idx<KS*8*VV; idx+=256){
    int m = idx/VV, rem = idx%VV;
    int v = rem/17, w = rem%17;
    AtileP[m*340 + v*20 + w] = A_SE[idx]+A_GEME[idx];
  }
}

// ---------------- K2b: per-n attention -> attenh[n][kk][q][v][20] (= 0.5*atten) ----------------
__global__ __launch_bounds__(256) void k2b_atten(
    const float* __restrict__ xbar,
    const float* __restrict__ Wq, const float* __restrict__ Wk,
    const float* __restrict__ bq, const float* __restrict__ bk,
    const float* __restrict__ W_spa, const float* __restrict__ b_spa,
    const float* __restrict__ W_mix, const float* __restrict__ b_mix,
    float* __restrict__ attenh){
  __shared__ float xb[CIN*V_];
  __shared__ float lWq[12*CIN], lWk[12*CIN], lbq[12], lbk[12];
  __shared__ float lWs[VV], lbs[V_], lWm[VV], lbm[V_];
  __shared__ float Qb[12*V_], Kb[12*V_], Qs[12*V_], Ks_[12*V_], Km[12*V_], Qm[12*V_];
  __shared__ float Sb[12*VV], Cb[9*VV];
  int tid = threadIdx.x;
  int n = blockIdx.x;
  for(int i=tid;i<CIN*V_;i+=256) xb[i]=xbar[n*CIN*V_+i];
  for(int i=tid;i<12*CIN;i+=256){ lWq[i]=Wq[i]; lWk[i]=Wk[i]; }
  if(tid<12){ lbq[tid]=bq[tid]; lbk[tid]=bk[tid]; }
  for(int i=tid;i<VV;i+=256){ lWs[i]=W_spa[i]; lWm[i]=W_mix[i]; }
  if(tid<V_){ lbs[tid]=b_spa[tid]; lbm[tid]=b_mix[tid]; }
  __syncthreads();
  if(tid<204){
    int kq=tid/17, v=tid%17;
    float qv=lbq[kq], kv=lbk[kq];
    for(int ci=0;ci<CIN;++ci){
      float xv = xb[ci*V_+v];
      qv += lWq[kq*CIN+ci]*xv;
      kv += lWk[kq*CIN+ci]*xv;
    }
    Qb[tid]=qv; Kb[tid]=kv;
  }
  __syncthreads();
  if(tid<204){
    int kq=tid/17, v=tid%17;
    float qs=lbs[v], ks=lbs[v], km=lbm[v], qm=lbm[v];
    #pragma unroll
    for(int u=0;u<V_;++u){
      float ws = lWs[v*V_+u], wm = lWm[v*V_+u];
      float qbu = Qb[kq*V_+u], kbu = Kb[kq*V_+u];
      qs += ws*qbu;
      ks += ws*kbu;
      km += wm*kbu;
      qm += wm*qbu;
    }
    Qs[tid]=fmaxf(qs,0.f); Ks_[tid]=fmaxf(ks,0.f); Km[tid]=fmaxf(km,0.f); Qm[tid]=fmaxf(qm,0.f);
  }
  __syncthreads();
  if(tid<204){
    int kq=tid/17, v=tid%17;
    float a=Qs[tid];
    float e[17]; float mx=-1e30f;
    #pragma unroll
    for(int w=0;w<V_;++w){ e[w]=a*Ks_[kq*V_+w]; mx=fmaxf(mx,e[w]); }
    float s=0.f;
    #pragma unroll
    for(int w=0;w<V_;++w){ e[w]=expf(e[w]-mx); s+=e[w]; }
    float inv=0.25f/s;
    #pragma unroll
    for(int w=0;w<V_;++w) Sb[kq*VV+v*V_+w]=e[w]*inv;
  }
  __syncthreads();
  if(tid<153){
    int kj=tid/17, v=tid%17;
    int k=kj/3, j=kj%3;
    float a=Km[(k*4+j)*V_+v];
    float e[17]; float mx=-1e30f;
    #pragma unroll
    for(int w=0;w<V_;++w){ e[w]=a*Qm[(k*4+j+1)*V_+w]; mx=fmaxf(mx,e[w]); }
    float s=0.f;
    #pragma unroll
    for(int w=0;w<V_;++w){ e[w]=expf(e[w]-mx); s+=e[w]; }
    float inv=0.125f/s;
    #pragma unroll
    for(int w=0;w<V_;++w) Cb[kj*VV+v*V_+w]=e[w]*inv;
  }
  __syncthreads();
  for(int idx=tid; idx<KS*4*VV; idx+=256){
    int kq=idx/VV, rem=idx%VV;
    int k=kq>>2, qq=kq&3;
    int v=rem/17, w=rem%17;
    float val=Sb[idx];
    if(qq>0) val += Cb[(k*3+qq-1)*VV+rem];
    if(qq<3) val += Cb[(k*3+qq)*VV+rem];
    attenh[(size_t)n*4080 + kq*340 + v*20 + w]=val;
  }
}

// ---------------- K3: fused conv + graph conv + stats + bf16 pack ----------------
// block = 512 threads = 128 c x 4 t; grid = (T/4, N).
// R3 lesson: 256-thread blocks at 51KB LDS -> ~8 waves/CU -> 36% VALUBusy
// (latency-bound). 512-thread blocks share the same table LDS across 8 waves:
// LDS allows 3 blocks (24 waves), VGPR cap 102 via launch_bounds(512,5) -> >=20.
// One acc[17] live at a time -> no spill (R2 lesson).
__global__ __launch_bounds__(512,5) void k3_main(
    const float* __restrict__ x0, const float* __restrict__ convwT,
    const float* __restrict__ conv_b, const float* __restrict__ down_b,
    const float* __restrict__ attenh, const float* __restrict__ AtileP,
    unsigned* __restrict__ mpack,
    float* __restrict__ s1ws, float* __restrict__ s2ws,
    float* __restrict__ dSws, float* __restrict__ dSSws){
  __shared__ float smem[12240];   // atten 4080 | Atile 8160 ; later aliased as staging [128][69]
  __shared__ float s1c[128], s2c[128], dSc[128], dSSc[128];
  const int tid = threadIdx.x;
  const int chunk = blockIdx.x, n = blockIdx.y;
  const int t0 = chunk*4;
  const int c = tid & 127;
  const int th = rf(tid>>7);           // wave-uniform timestep select (0..3)
  const int q = c>>5, g = c&7;

  {
    const float* ag = attenh + (size_t)n*4080;
    for(int i=tid;i<4080;i+=512) smem[i] = ag[i];
    for(int i=tid;i<8160;i+=512) smem[4080+i] = AtileP[i];
  }
  if(tid<128){ s1c[tid]=0.f; s2c[tid]=0.f; dSc[tid]=0.f; dSSc[tid]=0.f; }
  __syncthreads();

  const float* atq = smem + q*340;          // + kk*1360 + v*20 + w
  const float* tig = smem + 4080 + g*340;   // + kk*2720 + v*20 + w
  const float* xbase = x0 + (size_t)n*CIN*TV + (size_t)(t0 + th)*V_;  // wave-uniform rows

  float p[17];
  #pragma unroll
  for(int w=0;w<V_;++w) p[w]=0.f;

  // ---- kk = 0..2 : conv acc -> immediately folded into p ----
  for(int kk=0; kk<KS; ++kk){
    float acc[17];
    float b = conv_b[kk*128 + c];
    #pragma unroll
    for(int v=0;v<V_;++v) acc[v]=b;
    for(int ci=0; ci<CIN; ++ci){
      float wv = convwT[ci*512 + kk*128 + c];
      const float* xc = xbase + (size_t)ci*TV;
      #pragma unroll
      for(int v=0;v<V_;++v) acc[v] = fmaf(wv, xc[v], acc[v]);
    }
    const float* a1 = atq + kk*1360;
    const float* a2 = tig + kk*2720;
    #pragma unroll
    for(int v=0;v<V_;++v){
      float mv = acc[v];
      #pragma unroll
      for(int w=0;w<V_;++w)
        p[w] = fmaf(mv, a1[v*20+w] + a2[v*20+w], p[w]);
    }
  }

  // ---- down path ----
  float dn[17];
  {
    float b = down_b[c];
    #pragma unroll
    for(int v=0;v<V_;++v) dn[v]=b;
    for(int ci=0; ci<CIN; ++ci){
      float wv = convwT[ci*512 + 384 + c];
      const float* xc = xbase + (size_t)ci*TV;
      #pragma unroll
      for(int v=0;v<V_;++v) dn[v] = fmaf(wv, xc[v], dn[v]);
    }
  }

  // ---- stats on bf16-rounded values + pack ----
  unsigned pk[17];
  {
    float s=0.f, ss=0.f, sd=0.f, ssd=0.f;
    #pragma unroll
    for(int v=0;v<V_;++v){
      unsigned um = bf16r(p[v]);
      unsigned ud = bf16r(dn[v]);
      float rm = __uint_as_float(um<<16);
      float rd = __uint_as_float(ud<<16);
      pk[v] = um | (ud<<16);
      s += rm; ss = fmaf(rm,rm,ss); sd += rd; ssd = fmaf(rd,rd,ssd);
    }
    atomicAdd(&s1c[c], s); atomicAdd(&s2c[c], ss);
    atomicAdd(&dSc[c], sd); atomicAdd(&dSSc[c], ssd);
  }
  __syncthreads();   // tables fully consumed; LDS stats complete
  {
    unsigned* stg = (unsigned*)smem;   // [c][69 pad]
    #pragma unroll
    for(int v=0;v<V_;++v) stg[c*69 + th*V_ + v] = pk[v];
  }
  if(tid<128){
    atomicAdd(&s1ws[n*128+tid], s1c[tid]);
    atomicAdd(&s2ws[n*128+tid], s2c[tid]);
    atomicAdd(&dSws[tid], dSc[tid]);
    atomicAdd(&dSSws[tid], dSSc[tid]);
  }
  __syncthreads();
  {
    const unsigned* stg = (const unsigned*)smem;
    for(int idx=tid; idx<128*68; idx+=512){
      int cc = idx/68, r = idx - cc*68;
      mpack[(size_t)(n*128+cc)*TV + (size_t)t0*V_ + r] = stg[cc*69+r];
    }
  }
}

// ---------------- K4: gate + BN coefficient finalize ----------------
__global__ void k4_stats(const float* __restrict__ s1ws, const float* __restrict__ s2ws,
                         const float* __restrict__ dSws, const float* __restrict__ dSSws,
                         const float* __restrict__ charef_w,
                         const float* __restrict__ bn_gamma, const float* __restrict__ bn_beta,
                         const float* __restrict__ down_bn_gamma, const float* __restrict__ down_bn_beta,
                         float* __restrict__ g1ws, float* __restrict__ coef){
  int c = threadIdx.x;  // 128 threads
  float w0=charef_w[0], w1=charef_w[1], w2=charef_w[2];
  const float invTV = 1.f/(float)TV;
  float Sm=0.f, Sq=0.f;
  for(int n=0;n<N_;++n){
    float s1 = s1ws[n*128+c];
    float cr  = s1*invTV;
    float crm = (c>0)?   s1ws[n*128+c-1]*invTV : 0.f;
    float crp = (c<127)? s1ws[n*128+c+1]*invTV : 0.f;
    float cc = w0*crm + w1*cr + w2*crp;
    float g1 = 1.f + 1.f/(1.f+expf(-cc));   // 1 + sigmoid
    g1ws[n*128+c] = g1;
    Sm += s1*g1;
    Sq += s2ws[n*128+c]*g1*g1;
  }
  const float invNTV = 1.f/((float)N_*(float)TV);
  float mean = Sm*invNTV;
  float var  = Sq*invNTV - mean*mean;
  float sc = bn_gamma[c]*rsqrtf(var+1e-5f);
  coef[c]     = sc;
  coef[128+c] = bn_beta[c] - mean*sc;
  float mD = dSws[c]*invNTV;
  float vD = dSSws[c]*invNTV - mD*mD;
  float scD = down_bn_gamma[c]*rsqrtf(vD+1e-5f);
  coef[256+c] = scD;
  coef[384+c] = down_bn_beta[c] - mD*scD;
}

// ---------------- K5: elementwise unpack + affine + relu (in-place on d_out) ----------------
__global__ __launch_bounds__(256) void k5_out(
    const unsigned* mpack, const float* __restrict__ g1ws,
    const float* __restrict__ coef, float* out){
  int plane = blockIdx.x;          // n*128 + c
  int c = plane & 127;
  float a1  = coef[c] * g1ws[plane];
  float scD = coef[256+c];
  float b   = coef[128+c] + coef[384+c];
  const uint4* src = (const uint4*)(mpack + (size_t)plane*TV);
  float4* dst = (float4*)(out + (size_t)plane*TV);
  for(int i=threadIdx.x; i<TV/4; i+=256){
    uint4 w = src[i];
    float4 r;
    r.x = fmaxf(fmaf(a1, __uint_as_float(w.x<<16), fmaf(scD, __uint_as_float(w.x&0xffff0000u), b)), 0.f);
    r.y = fmaxf(fmaf(a1, __uint_as_float(w.y<<16), fmaf(scD, __uint_as_float(w.y&0xffff0000u), b)), 0.f);
    r.z = fmaxf(fmaf(a1, __uint_as_float(w.z<<16), fmaf(scD, __uint_as_float(w.z&0xffff0000u), b)), 0.f);
    r.w = fmaxf(fmaf(a1, __uint_as_float(w.w<<16), fmaf(scD, __uint_as_float(w.w&0xffff0000u), b)), 0.f);
    dst[i] = r;
  }
}

extern "C" void kernel_launch(void* const* d_in, const int* in_sizes, int n_in,
                              void* d_out, int out_size, void* d_ws, size_t ws_size,
                              hipStream_t stream){
  const float* x0      = (const float*)d_in[0];
  const float* conv_w  = (const float*)d_in[1];
  const float* conv_b  = (const float*)d_in[2];
  const float* W_spa   = (const float*)d_in[3];
  const float* b_spa   = (const float*)d_in[4];
  const float* W_mix   = (const float*)d_in[5];
  const float* b_mix   = (const float*)d_in[6];
  const float* A_GEME  = (const float*)d_in[7];
  const float* A_SE    = (const float*)d_in[8];
  const float* charef_w= (const float*)d_in[9];
  const float* bn_gamma= (const float*)d_in[10];
  const float* bn_beta = (const float*)d_in[11];
  const float* down_w  = (const float*)d_in[12];
  const float* down_b  = (const float*)d_in[13];
  const float* down_bn_gamma = (const float*)d_in[14];
  const float* down_bn_beta  = (const float*)d_in[15];
  float* out = (float*)d_out;
  float* ws  = (float*)d_ws;

  float* xbar   = ws;                 // 69632
  float* convwT = xbar + 69632;       // 32768
  float* Wq     = convwT + 32768;     // 768
  float* Wk     = Wq + 768;           // 768
  float* bq     = Wk + 768;           // 12
  float* bk     = bq + 12;            // 12
  float* AtileP = bk + 12;            // 8160
  float* attenh = AtileP + 8160;      // 64*4080 = 261120
  float* s1ws   = attenh + 261120;    // 8192  -- accumulators (memset region start)
  float* s2ws   = s1ws + 8192;        // 8192
  float* dSws   = s2ws + 8192;        // 128
  float* dSSws  = dSws + 128;         // 128   -- memset region end (16640 floats)
  float* g1ws   = dSSws + 128;        // 8192
  float* coef   = g1ws + 8192;        // 512

  hipMemsetAsync(s1ws, 0, (size_t)16640*sizeof(float), stream);
  k1_pool<<<dim3(N_*CIN), dim3(17,15), 0, stream>>>(x0, xbar);
  k2a_prep<<<1, 256, 0, stream>>>(conv_w, conv_b, down_w, A_GEME, A_SE,
                                  convwT, Wq, Wk, bq, bk, AtileP);
  k2b_atten<<<N_, 256, 0, stream>>>(xbar, Wq, Wk, bq, bk, W_spa, b_spa, W_mix, b_mix, attenh);
  k3_main<<<dim3(T_/4, N_), 512, 0, stream>>>(x0, convwT, conv_b, down_b, attenh, AtileP,
                                              (unsigned*)out, s1ws, s2ws, dSws, dSSws);
  k4_stats<<<1, 128, 0, stream>>>(s1ws, s2ws, dSws, dSSws, charef_w,
                                  bn_gamma, bn_beta, down_bn_gamma, down_bn_beta, g1ws, coef);
  k5_out<<<dim3(N_*OUT_), 256, 0, stream>>>((const unsigned*)out, g1ws, coef, out);
}